// Round 8
// baseline (247.397 us; speedup 1.0000x reference)
//
#include <hip/hip_runtime.h>
#include <hip/hip_bf16.h>
#include <math.h>

#define D 100
#define NEG_SLOPE 0.2f
#define CHUNK 16
#define ROWU 50          // uints per staged bf16 row (100 dims * 2B / 4B)

// pack two fp32 -> (bf16lo,bf16hi) uint, RNE (hardware packed cvt on gfx950)
__device__ __forceinline__ unsigned int pk2(float x, float y) {
    union { __hip_bfloat162 h2; unsigned int u; } cv;
    cv.h2 = __float22bfloat162_rn(make_float2(x, y));
    return cv.u;
}

__device__ __forceinline__ uint2 pk(float4 b) {
    return make_uint2(pk2(b.x, b.y), pk2(b.z, b.w));
}

__device__ __forceinline__ float dot4(float4 a, float4 b) {
    return a.x * b.x + a.y * b.y + a.z * b.z + a.w * b.w;
}

// Pair-parallel boundary scatter: row_ptr[v] = first pair index with seg >= v.
__global__ void build_row_ptr(const int* __restrict__ seg,
                              int* __restrict__ row_ptr,
                              int n, int P)
{
    int p = blockIdx.x * blockDim.x + threadIdx.x;
    if (p >= P) return;
    int s0 = seg[p];
    if (p == 0)
        for (int v = 0; v <= s0; v++) row_ptr[v] = 0;
    int s1 = (p + 1 < P) ? seg[p + 1] : n;
    for (int v = s0 + 1; v <= s1; v++) row_ptr[v] = p + 1;
}

// One wave per node. CHUNK=16, 4 lanes per pair (quarter-rows 7/6/6/6 float4s)
// -> LDS 14.7 KB/block -> 8 blocks/CU (32 waves, 2x R7). Grouped loads fenced
// with sched_barrier(0) to keep VGPR<=64 (no scratch spill — R5/R6 lesson).
__launch_bounds__(256, 8)
__global__ void gat_agg_kernel(const float* __restrict__ hidden,
                               const float* __restrict__ W,
                               const int* __restrict__ nbr,
                               const int* __restrict__ row_ptr,
                               float* __restrict__ out,
                               int n)
{
    __shared__ __align__(16) float        s_hw[4][104];           // 1.66 KB
    __shared__ __align__(16) unsigned int s_rows[4][CHUNK][ROWU]; // 12.8 KB
    __shared__ __align__(16) float        s_e[4][CHUNK];          // 0.25 KB

    const int lane = threadIdx.x & 63;
    const int wid  = threadIdx.x >> 6;
    const int v    = blockIdx.x * 4 + wid;
    if (v >= n) return;          // wave-uniform exit; no block barriers used

    // hw[d] = hidden[v][d] * W[d], staged once in LDS (broadcast source)
    s_hw[wid][lane] = hidden[(long)v * D + lane] * W[lane];
    if (lane < D - 64)
        s_hw[wid][64 + lane] = hidden[(long)v * D + 64 + lane] * W[64 + lane];
    __threadfence_block();

    const float4* hw4 = (const float4*)&s_hw[wid][0];

    const int start = row_ptr[v];
    const int end   = row_ptr[v + 1];

    if (end <= start) {          // empty segment: zeros (matches reference)
        if (lane < D / 2)
            ((float2*)(out + (long)v * D))[lane] = make_float2(0.f, 0.f);
        return;
    }

    const int q    = lane >> 4;               // quarter 0..3
    const int jl   = lane & 15;               // pair slot within the 16-chunk
    const int offs = 6 * q + (q ? 1 : 0);     // float4 offset: 0,7,13,19
    // quarter float4 counts: 7,6,6,6 (q0 takes the odd 25th float4)

    float m = -INFINITY, z = 0.f;
    float accx = 0.f, accy = 0.f;

    for (int c = start; c < end; c += CHUNK) {
        const int  cnt = min(CHUNK, end - c);
        const bool pv  = jl < cnt;

        // invalid lanes gather row 0 (finite, in-bounds); e=0 masks it later
        const int nbv = pv ? nbr[c + jl] : 0;
        const float4* row4 = (const float4*)(hidden + (long)nbv * D) + offs;
        const float4* hwh  = hw4 + offs;
        uint2* dst = (uint2*)&s_rows[wid][jl][offs * 2];

        // ---- Phase A: quarter-row gather-dot + bf16 stage, fenced groups ----
        float4 x0 = row4[0], x1 = row4[1], x2 = row4[2], x3 = row4[3];
        float p0 = dot4(hwh[0], x0); dst[0] = pk(x0);
        float p1 = dot4(hwh[1], x1); dst[1] = pk(x1);
        __builtin_amdgcn_sched_barrier(0);   // cap live-range hoisting

        float4 x4 = row4[4], x5 = row4[5];
        float4 x6;
        if (q == 0) x6 = row4[6];            // 25th float4, quarter 0 only
        float p2 = dot4(hwh[2], x2); dst[2] = pk(x2);
        float p3 = dot4(hwh[3], x3); dst[3] = pk(x3);
        __builtin_amdgcn_sched_barrier(0);

        p0 += dot4(hwh[4], x4); dst[4] = pk(x4);
        p1 += dot4(hwh[5], x5); dst[5] = pk(x5);
        if (q == 0) { p2 += dot4(hw4[6], x6); dst[6] = pk(x6); }

        float part = (p0 + p1) + (p2 + p3);
        part += __shfl_xor(part, 16, 64);    // combine quarters
        part += __shfl_xor(part, 32, 64);
        const float s = pv ? (part >= 0.f ? part : NEG_SLOPE * part)
                           : -INFINITY;

        // ---- online softmax: s duplicated across quarters -> 4-step reductions
        float mx = s;
        #pragma unroll
        for (int off = 8; off >= 1; off >>= 1)
            mx = fmaxf(mx, __shfl_xor(mx, off, 64));
        const float m_new = fmaxf(m, mx);
        const float scale = __expf(m - m_new);         // first chunk: 0
        const float e     = pv ? __expf(s - m_new) : 0.f;
        float es = e;
        #pragma unroll
        for (int off = 8; off >= 1; off >>= 1)
            es += __shfl_xor(es, off, 64);             // sum within 16-group
        z = z * scale + es;
        accx *= scale; accy *= scale;

        if (lane < CHUNK) s_e[wid][lane] = e;          // q0 lanes: jl == lane
        __threadfence_block();                         // LDS stores -> reads

        // ---- Phase B: lane-per-dim accumulate from bf16 LDS ----
        const int cnt4 = (cnt + 3) & ~3;               // <= 16
        if (lane < D / 2) {
            for (int j0 = 0; j0 < cnt4; j0 += 4) {
                const float4 ev = *(const float4*)&s_e[wid][j0];  // broadcast
                const unsigned int u0 = s_rows[wid][j0    ][lane];
                const unsigned int u1 = s_rows[wid][j0 + 1][lane];
                const unsigned int u2 = s_rows[wid][j0 + 2][lane];
                const unsigned int u3 = s_rows[wid][j0 + 3][lane];
                accx += ev.x * __uint_as_float(u0 << 16);
                accy += ev.x * __uint_as_float(u0 & 0xFFFF0000u);
                accx += ev.y * __uint_as_float(u1 << 16);
                accy += ev.y * __uint_as_float(u1 & 0xFFFF0000u);
                accx += ev.z * __uint_as_float(u2 << 16);
                accy += ev.z * __uint_as_float(u2 & 0xFFFF0000u);
                accx += ev.w * __uint_as_float(u3 << 16);
                accy += ev.w * __uint_as_float(u3 & 0xFFFF0000u);
            }
        }
        __threadfence_block();   // phase-B reads done before next chunk's stores
        m = m_new;
    }

    if (lane < D / 2) {
        const float inv = 1.f / z;
        ((float2*)(out + (long)v * D))[lane] = make_float2(accx * inv, accy * inv);
    }
}

extern "C" void kernel_launch(void* const* d_in, const int* in_sizes, int n_in,
                              void* d_out, int out_size, void* d_ws, size_t ws_size,
                              hipStream_t stream) {
    const float* hidden = (const float*)d_in[0];
    const float* W      = (const float*)d_in[1];
    const int*   seg    = (const int*)d_in[2];
    const int*   nbr    = (const int*)d_in[3];
    float*       out    = (float*)d_out;

    const int Ddim = in_sizes[1];           // 100
    const int n    = in_sizes[0] / Ddim;    // 50000
    const int P    = in_sizes[2];           // ~1.3M pairs

    int* row_ptr = (int*)d_ws;              // (n+1) ints

    hipLaunchKernelGGL(build_row_ptr, dim3((P + 255) / 256), dim3(256), 0, stream,
                       seg, row_ptr, n, P);
    hipLaunchKernelGGL(gat_agg_kernel, dim3((n + 3) / 4), dim3(256), 0, stream,
                       hidden, W, nbr, row_ptr, out, n);
}

// Round 9
// 164.049 us; speedup vs baseline: 1.5081x; 1.5081x over previous
//
#include <hip/hip_runtime.h>
#include <hip/hip_bf16.h>
#include <math.h>

#define D 100
#define NEG_SLOPE 0.2f
#define CHUNK 16
#define ROWU 50          // uints per staged bf16 row (100 dims * 2B / 4B)

// pack two fp32 -> (bf16lo,bf16hi) uint, RNE (hardware packed cvt on gfx950)
__device__ __forceinline__ unsigned int pk2(float x, float y) {
    union { __hip_bfloat162 h2; unsigned int u; } cv;
    cv.h2 = __float22bfloat162_rn(make_float2(x, y));
    return cv.u;
}

__device__ __forceinline__ uint2 pk(float4 b) {
    return make_uint2(pk2(b.x, b.y), pk2(b.z, b.w));
}

__device__ __forceinline__ float dot4(float4 a, float4 b) {
    return a.x * b.x + a.y * b.y + a.z * b.z + a.w * b.w;
}

// Pair-parallel boundary scatter: row_ptr[v] = first pair index with seg >= v.
__global__ void build_row_ptr(const int* __restrict__ seg,
                              int* __restrict__ row_ptr,
                              int n, int P)
{
    int p = blockIdx.x * blockDim.x + threadIdx.x;
    if (p >= P) return;
    int s0 = seg[p];
    if (p == 0)
        for (int v = 0; v <= s0; v++) row_ptr[v] = 0;
    int s1 = (p + 1 < P) ? seg[p + 1] : n;
    for (int v = s0 + 1; v <= s1; v++) row_ptr[v] = p + 1;
}

// One wave per node. CHUNK=16, 4 lanes per pair (quarter-rows 7/6/6/6 float4s).
// LDS 14.8 KB/block; occupancy limiter is launch bounds: 6 waves/EU = 75%.
// VGPR cap 85 — the (256,8)=64 cap spilled (R8: WRITE_SIZE 290 MB); the
// quarter scheme's live set is ~70 regs, needs the 85 headroom.
__launch_bounds__(256, 6)
__global__ void gat_agg_kernel(const float* __restrict__ hidden,
                               const float* __restrict__ W,
                               const int* __restrict__ nbr,
                               const int* __restrict__ row_ptr,
                               float* __restrict__ out,
                               int n)
{
    __shared__ __align__(16) float        s_hw[4][104];           // 1.66 KB
    __shared__ __align__(16) unsigned int s_rows[4][CHUNK][ROWU]; // 12.8 KB
    __shared__ __align__(16) float        s_e[4][CHUNK];          // 0.25 KB

    const int lane = threadIdx.x & 63;
    const int wid  = threadIdx.x >> 6;
    const int v    = blockIdx.x * 4 + wid;
    if (v >= n) return;          // wave-uniform exit; no block barriers used

    // hw[d] = hidden[v][d] * W[d], staged once in LDS (broadcast source)
    s_hw[wid][lane] = hidden[(long)v * D + lane] * W[lane];
    if (lane < D - 64)
        s_hw[wid][64 + lane] = hidden[(long)v * D + 64 + lane] * W[64 + lane];
    __threadfence_block();

    const float4* hw4 = (const float4*)&s_hw[wid][0];

    const int start = row_ptr[v];
    const int end   = row_ptr[v + 1];

    if (end <= start) {          // empty segment: zeros (matches reference)
        if (lane < D / 2)
            ((float2*)(out + (long)v * D))[lane] = make_float2(0.f, 0.f);
        return;
    }

    const int q    = lane >> 4;               // quarter 0..3
    const int jl   = lane & 15;               // pair slot within the 16-chunk
    const int offs = 6 * q + (q ? 1 : 0);     // float4 offset: 0,7,13,19
    // quarter float4 counts: 7,6,6,6 (q0 takes the odd 25th float4)

    float m = -INFINITY, z = 0.f;
    float accx = 0.f, accy = 0.f;

    for (int c = start; c < end; c += CHUNK) {
        const int  cnt = min(CHUNK, end - c);
        const bool pv  = jl < cnt;

        // invalid lanes gather row 0 (finite, in-bounds); e=0 masks it later
        const int nbv = pv ? nbr[c + jl] : 0;
        const float4* row4 = (const float4*)(hidden + (long)nbv * D) + offs;
        const float4* hwh  = hw4 + offs;
        uint2* dst = (uint2*)&s_rows[wid][jl][offs * 2];

        // ---- Phase A: quarter-row gather-dot + bf16 stage, fenced groups ----
        float4 x0 = row4[0], x1 = row4[1], x2 = row4[2], x3 = row4[3];
        float p0 = dot4(hwh[0], x0); dst[0] = pk(x0);
        float p1 = dot4(hwh[1], x1); dst[1] = pk(x1);
        __builtin_amdgcn_sched_barrier(0);   // cap live-range hoisting

        float4 x4 = row4[4], x5 = row4[5];
        float4 x6;
        if (q == 0) x6 = row4[6];            // 25th float4, quarter 0 only
        float p2 = dot4(hwh[2], x2); dst[2] = pk(x2);
        float p3 = dot4(hwh[3], x3); dst[3] = pk(x3);
        __builtin_amdgcn_sched_barrier(0);

        p0 += dot4(hwh[4], x4); dst[4] = pk(x4);
        p1 += dot4(hwh[5], x5); dst[5] = pk(x5);
        if (q == 0) { p2 += dot4(hw4[6], x6); dst[6] = pk(x6); }

        float part = (p0 + p1) + (p2 + p3);
        part += __shfl_xor(part, 16, 64);    // combine quarters
        part += __shfl_xor(part, 32, 64);
        const float s = pv ? (part >= 0.f ? part : NEG_SLOPE * part)
                           : -INFINITY;

        // ---- online softmax: s duplicated across quarters -> 4-step reductions
        float mx = s;
        #pragma unroll
        for (int off = 8; off >= 1; off >>= 1)
            mx = fmaxf(mx, __shfl_xor(mx, off, 64));
        const float m_new = fmaxf(m, mx);
        const float scale = __expf(m - m_new);         // first chunk: 0
        const float e     = pv ? __expf(s - m_new) : 0.f;
        float es = e;
        #pragma unroll
        for (int off = 8; off >= 1; off >>= 1)
            es += __shfl_xor(es, off, 64);             // sum within 16-group
        z = z * scale + es;
        accx *= scale; accy *= scale;

        if (lane < CHUNK) s_e[wid][lane] = e;          // q0 lanes: jl == lane
        __threadfence_block();                         // LDS stores -> reads

        // ---- Phase B: lane-per-dim accumulate from bf16 LDS ----
        const int cnt4 = (cnt + 3) & ~3;               // <= 16
        if (lane < D / 2) {
            for (int j0 = 0; j0 < cnt4; j0 += 4) {
                const float4 ev = *(const float4*)&s_e[wid][j0];  // broadcast
                const unsigned int u0 = s_rows[wid][j0    ][lane];
                const unsigned int u1 = s_rows[wid][j0 + 1][lane];
                const unsigned int u2 = s_rows[wid][j0 + 2][lane];
                const unsigned int u3 = s_rows[wid][j0 + 3][lane];
                accx += ev.x * __uint_as_float(u0 << 16);
                accy += ev.x * __uint_as_float(u0 & 0xFFFF0000u);
                accx += ev.y * __uint_as_float(u1 << 16);
                accy += ev.y * __uint_as_float(u1 & 0xFFFF0000u);
                accx += ev.z * __uint_as_float(u2 << 16);
                accy += ev.z * __uint_as_float(u2 & 0xFFFF0000u);
                accx += ev.w * __uint_as_float(u3 << 16);
                accy += ev.w * __uint_as_float(u3 & 0xFFFF0000u);
            }
        }
        __threadfence_block();   // phase-B reads done before next chunk's stores
        m = m_new;
    }

    if (lane < D / 2) {
        const float inv = 1.f / z;
        ((float2*)(out + (long)v * D))[lane] = make_float2(accx * inv, accy * inv);
    }
}

extern "C" void kernel_launch(void* const* d_in, const int* in_sizes, int n_in,
                              void* d_out, int out_size, void* d_ws, size_t ws_size,
                              hipStream_t stream) {
    const float* hidden = (const float*)d_in[0];
    const float* W      = (const float*)d_in[1];
    const int*   seg    = (const int*)d_in[2];
    const int*   nbr    = (const int*)d_in[3];
    float*       out    = (float*)d_out;

    const int Ddim = in_sizes[1];           // 100
    const int n    = in_sizes[0] / Ddim;    // 50000
    const int P    = in_sizes[2];           // ~1.3M pairs

    int* row_ptr = (int*)d_ws;              // (n+1) ints

    hipLaunchKernelGGL(build_row_ptr, dim3((P + 255) / 256), dim3(256), 0, stream,
                       seg, row_ptr, n, P);
    hipLaunchKernelGGL(gat_agg_kernel, dim3((n + 3) / 4), dim3(256), 0, stream,
                       hidden, W, nbr, row_ptr, out, n);
}

// Round 11
// 143.095 us; speedup vs baseline: 1.7289x; 1.1464x over previous
//
#include <hip/hip_runtime.h>
#include <hip/hip_bf16.h>
#include <math.h>

#define D 100
#define NEG_SLOPE 0.2f
#define CHUNK 16
#define ROWU 52          // uints per bf16 row, padded 50->52 for 16B alignment

// pack two fp32 -> (bf16lo,bf16hi) uint, RNE
__device__ __forceinline__ unsigned int pk2(float x, float y) {
    union { __hip_bfloat162 h2; unsigned int u; } cv;
    cv.h2 = __float22bfloat162_rn(make_float2(x, y));
    return cv.u;
}
__device__ __forceinline__ float blo(unsigned int u) { return __uint_as_float(u << 16); }
__device__ __forceinline__ float bhi(unsigned int u) { return __uint_as_float(u & 0xFFFF0000u); }

// Pair-parallel boundary scatter: row_ptr[v] = first pair index with seg >= v.
__global__ void build_row_ptr(const int* __restrict__ seg,
                              int* __restrict__ row_ptr,
                              int n, int P)
{
    int p = blockIdx.x * blockDim.x + threadIdx.x;
    if (p >= P) return;
    int s0 = seg[p];
    if (p == 0)
        for (int v = 0; v <= s0; v++) row_ptr[v] = 0;
    int s1 = (p + 1 < P) ? seg[p + 1] : n;
    for (int v = s0 + 1; v <= s1; v++) row_ptr[v] = p + 1;
}

// hidden (fp32, rows of 100) -> packed bf16 rows of ROWU uints (padded).
__global__ void cvt_hidden(const float* __restrict__ hidden,
                           unsigned int* __restrict__ hb, int total /* n*25 */)
{
    int t = blockIdx.x * blockDim.x + threadIdx.x;
    if (t >= total) return;
    int node = t / 25, k = t - node * 25;       // 25 float4-groups per row
    float4 f = ((const float4*)hidden)[node * 25 + k];
    *(uint2*)&hb[node * ROWU + 2 * k] = make_uint2(pk2(f.x, f.y), pk2(f.z, f.w));
}

// dot of one bf16-packed uint4 (8 dims) against 2 fp32 float4s from LDS,
// spread over 4 accumulators
__device__ __forceinline__ void acc8(uint4 xv, float4 a0, float4 a1,
                                     float& p0, float& p1, float& p2, float& p3) {
    p0 += a0.x * blo(xv.x) + a0.y * bhi(xv.x);
    p1 += a0.z * blo(xv.y) + a0.w * bhi(xv.y);
    p2 += a1.x * blo(xv.z) + a1.y * bhi(xv.z);
    p3 += a1.z * blo(xv.w) + a1.w * bhi(xv.w);
}

// One wave per node. CHUNK=16, 4 lanes/pair; phase A gathers the BF16 copy
// (200 B/row, half the fp32 traffic; 3x uint4 + tail per lane), dots via
// unpack+FMA (h_i*W side stays exact fp32), stages raw uint4s to LDS.
// Phase B: lane-per-dim accumulate from bf16 LDS (unchanged from R9).
__launch_bounds__(256, 6)   // cap 85 proved spill-free (R9, VGPR=40); (256,8) spilled (R8)
__global__ void gat_agg_kernel(const float* __restrict__ hidden,
                               const float* __restrict__ W,
                               const int* __restrict__ nbr,
                               const int* __restrict__ row_ptr,
                               const unsigned int* __restrict__ hb,
                               float* __restrict__ out,
                               int n)
{
    __shared__ __align__(16) float        s_hw[4][104];           // 1.66 KB
    __shared__ __align__(16) unsigned int s_rows[4][CHUNK][ROWU]; // 13.3 KB
    __shared__ __align__(16) float        s_e[4][CHUNK];          // 0.25 KB

    const int lane = threadIdx.x & 63;
    const int wid  = threadIdx.x >> 6;
    const int v    = blockIdx.x * 4 + wid;
    if (v >= n) return;          // wave-uniform exit; no block barriers used

    // hw[d] = hidden[v][d] * W[d], fp32 exact, staged once in LDS
    s_hw[wid][lane] = hidden[(long)v * D + lane] * W[lane];
    if (lane < D - 64)
        s_hw[wid][64 + lane] = hidden[(long)v * D + 64 + lane] * W[64 + lane];
    __threadfence_block();

    const float4* hw4 = (const float4*)&s_hw[wid][0];

    const int start = row_ptr[v];
    const int end   = row_ptr[v + 1];

    if (end <= start) {          // empty segment: zeros (matches reference)
        if (lane < D / 2)
            ((float2*)(out + (long)v * D))[lane] = make_float2(0.f, 0.f);
        return;
    }

    const int q  = lane >> 4;    // quarter 0..3: uint4s q*3..q*3+2 (+tail on q0)
    const int jl = lane & 15;    // pair slot within the 16-chunk
    const int t0 = q * 3;

    float m = -INFINITY, z = 0.f;
    float accx = 0.f, accy = 0.f;

    for (int c = start; c < end; c += CHUNK) {
        const int  cnt = min(CHUNK, end - c);
        const bool pv  = jl < cnt;

        // invalid lanes gather row 0 (finite, in-bounds); e=0 masks it later
        const int nbv = pv ? nbr[c + jl] : 0;
        const uint4* row16 = ((const uint4*)hb) + nbv * (ROWU / 4) + t0;

        // ---- Phase A: bf16 quarter-row gather (3x16B + 8B tail) ----
        uint4 x0 = row16[0], x1 = row16[1], x2 = row16[2];
        uint2 xt;
        if (q == 0) xt = *(const uint2*)&hb[nbv * ROWU + 48];   // dims 96..99

        float p0 = 0.f, p1 = 0.f, p2 = 0.f, p3 = 0.f;
        acc8(x0, hw4[2*t0    ], hw4[2*t0 + 1], p0, p1, p2, p3);
        acc8(x1, hw4[2*t0 + 2], hw4[2*t0 + 3], p0, p1, p2, p3);
        acc8(x2, hw4[2*t0 + 4], hw4[2*t0 + 5], p0, p1, p2, p3);
        if (q == 0) {
            float4 a = hw4[24];
            p0 += a.x * blo(xt.x) + a.y * bhi(xt.x);
            p1 += a.z * blo(xt.y) + a.w * bhi(xt.y);
        }

        // stage raw bf16 row to LDS (16B-aligned: ROWU*4 = 208 = 13*16)
        uint4* dst16 = ((uint4*)&s_rows[wid][jl][0]) + t0;
        dst16[0] = x0; dst16[1] = x1; dst16[2] = x2;
        if (q == 0) *(uint2*)&s_rows[wid][jl][48] = xt;

        float part = (p0 + p1) + (p2 + p3);
        part += __shfl_xor(part, 16, 64);    // combine quarters
        part += __shfl_xor(part, 32, 64);
        const float s = pv ? (part >= 0.f ? part : NEG_SLOPE * part)
                           : -INFINITY;

        // ---- online softmax: s duplicated across quarters -> 4-step reductions
        float mx = s;
        #pragma unroll
        for (int off = 8; off >= 1; off >>= 1)
            mx = fmaxf(mx, __shfl_xor(mx, off, 64));
        const float m_new = fmaxf(m, mx);
        const float scale = __expf(m - m_new);         // first chunk: 0
        const float e     = pv ? __expf(s - m_new) : 0.f;
        float es = e;
        #pragma unroll
        for (int off = 8; off >= 1; off >>= 1)
            es += __shfl_xor(es, off, 64);             // sum within 16-group
        z = z * scale + es;
        accx *= scale; accy *= scale;

        if (lane < CHUNK) s_e[wid][lane] = e;          // q0 lanes: jl == lane
        __threadfence_block();                         // LDS stores -> reads

        // ---- Phase B: lane-per-dim accumulate from bf16 LDS ----
        const int cnt4 = (cnt + 3) & ~3;               // <= 16
        if (lane < D / 2) {
            for (int j0 = 0; j0 < cnt4; j0 += 4) {
                const float4 ev = *(const float4*)&s_e[wid][j0];  // broadcast
                const unsigned int u0 = s_rows[wid][j0    ][lane];
                const unsigned int u1 = s_rows[wid][j0 + 1][lane];
                const unsigned int u2 = s_rows[wid][j0 + 2][lane];
                const unsigned int u3 = s_rows[wid][j0 + 3][lane];
                accx += ev.x * blo(u0);  accy += ev.x * bhi(u0);
                accx += ev.y * blo(u1);  accy += ev.y * bhi(u1);
                accx += ev.z * blo(u2);  accy += ev.z * bhi(u2);
                accx += ev.w * blo(u3);  accy += ev.w * bhi(u3);
            }
        }
        __threadfence_block();   // phase-B reads done before next chunk's stores
        m = m_new;
    }

    if (lane < D / 2) {
        const float inv = 1.f / z;
        ((float2*)(out + (long)v * D))[lane] = make_float2(accx * inv, accy * inv);
    }
}

extern "C" void kernel_launch(void* const* d_in, const int* in_sizes, int n_in,
                              void* d_out, int out_size, void* d_ws, size_t ws_size,
                              hipStream_t stream) {
    const float* hidden = (const float*)d_in[0];
    const float* W      = (const float*)d_in[1];
    const int*   seg    = (const int*)d_in[2];
    const int*   nbr    = (const int*)d_in[3];
    float*       out    = (float*)d_out;

    const int Ddim = in_sizes[1];           // 100
    const int n    = in_sizes[0] / Ddim;    // 50000
    const int P    = in_sizes[2];           // ~1.3M pairs

    // ws layout: row_ptr (n+1 ints) | hb (n*ROWU uints, 256B-aligned)
    int* row_ptr = (int*)d_ws;
    size_t hb_off = (((size_t)(n + 1) * 4) + 255) & ~(size_t)255;
    unsigned int* hb = (unsigned int*)((char*)d_ws + hb_off);

    hipLaunchKernelGGL(build_row_ptr, dim3((P + 255) / 256), dim3(256), 0, stream,
                       seg, row_ptr, n, P);
    const int total = n * 25;               // float4-groups in hidden
    hipLaunchKernelGGL(cvt_hidden, dim3((total + 255) / 256), dim3(256), 0, stream,
                       hidden, hb, total);
    hipLaunchKernelGGL(gat_agg_kernel, dim3((n + 3) / 4), dim3(256), 0, stream,
                       hidden, W, nbr, row_ptr, hb, out, n);
}

// Round 12
// 133.920 us; speedup vs baseline: 1.8473x; 1.0685x over previous
//
#include <hip/hip_runtime.h>
#include <math.h>

#define D 100
#define NEG_SLOPE 0.2f
#define CHUNK 16
#define ROWU 52          // uints per packed-f16 row, padded 50->52 for 16B align

typedef _Float16 f16x2 __attribute__((ext_vector_type(2)));
union U32H2 { unsigned int u; f16x2 h; };

__device__ __forceinline__ unsigned int pkh2(float x, float y) {
    U32H2 c; c.h.x = (_Float16)x; c.h.y = (_Float16)y; return c.u;
}
__device__ __forceinline__ float f16lo(unsigned int u) { U32H2 c; c.u = u; return (float)c.h.x; }
__device__ __forceinline__ float f16hi(unsigned int u) { U32H2 c; c.u = u; return (float)c.h.y; }

// 2-wide f16 dot + fp32 accumulate: v_dot2_f32_f16 (1 VALU inst vs 4)
__device__ __forceinline__ float dot2u(unsigned int au, unsigned int xu, float acc) {
#if __has_builtin(__builtin_amdgcn_fdot2)
    U32H2 a, x; a.u = au; x.u = xu;
    return __builtin_amdgcn_fdot2(a.h, x.h, acc, false);
#else
    return acc + f16lo(au) * f16lo(xu) + f16hi(au) * f16hi(xu);
#endif
}

// Pair-parallel boundary scatter: row_ptr[v] = first pair index with seg >= v.
__global__ void build_row_ptr(const int* __restrict__ seg,
                              int* __restrict__ row_ptr,
                              int n, int P)
{
    int p = blockIdx.x * blockDim.x + threadIdx.x;
    if (p >= P) return;
    int s0 = seg[p];
    if (p == 0)
        for (int v = 0; v <= s0; v++) row_ptr[v] = 0;
    int s1 = (p + 1 < P) ? seg[p + 1] : n;
    for (int v = s0 + 1; v <= s1; v++) row_ptr[v] = p + 1;
}

// hidden (fp32, rows of 100) -> packed f16 rows of ROWU uints (padded).
__global__ void cvt_hidden(const float* __restrict__ hidden,
                           unsigned int* __restrict__ hb, int total /* n*25 */)
{
    int t = blockIdx.x * blockDim.x + threadIdx.x;
    if (t >= total) return;
    int node = t / 25, k = t - node * 25;       // 25 float4-groups per row
    float4 f = ((const float4*)hidden)[node * 25 + k];
    *(uint2*)&hb[node * ROWU + 2 * k] = make_uint2(pkh2(f.x, f.y), pkh2(f.z, f.w));
}

// One wave per node. CHUNK=16, 4 lanes/pair. Phase A: gather the f16 copy
// (200 B/row), score via v_dot2_f32_f16 against f16-packed hw in LDS
// (~4x fewer VALU ops than unpack+FMA — R11 was VALU-issue-bound), stage raw
// uint4s to LDS. Phase B: lane-per-dim accumulate, f16 unpack (v_cvt).
__launch_bounds__(256, 7)   // 28 waves/CU; VGPR cap 73 (R11 used 40 — margin)
__global__ void gat_agg_kernel(const float* __restrict__ hidden,
                               const float* __restrict__ W,
                               const int* __restrict__ nbr,
                               const int* __restrict__ row_ptr,
                               const unsigned int* __restrict__ hb,
                               float* __restrict__ out,
                               int n)
{
    __shared__ __align__(16) unsigned int s_hwp[4][ROWU];         // 0.83 KB
    __shared__ __align__(16) unsigned int s_rows[4][CHUNK][ROWU]; // 13.3 KB
    __shared__ __align__(16) float        s_e[4][CHUNK];          // 0.25 KB

    const int lane = threadIdx.x & 63;
    const int wid  = threadIdx.x >> 6;
    const int v    = blockIdx.x * 4 + wid;
    if (v >= n) return;          // wave-uniform exit; no block barriers used

    // hw[d] = hidden[v][d] * W[d] (fp32 product, f16-packed into LDS)
    if (lane < 50) {
        float2 h2 = ((const float2*)(hidden + (long)v * D))[lane];
        float2 w2 = ((const float2*)W)[lane];
        s_hwp[wid][lane] = pkh2(h2.x * w2.x, h2.y * w2.y);
    }
    __threadfence_block();

    const int start = row_ptr[v];
    const int end   = row_ptr[v + 1];

    if (end <= start) {          // empty segment: zeros (matches reference)
        if (lane < D / 2)
            ((float2*)(out + (long)v * D))[lane] = make_float2(0.f, 0.f);
        return;
    }

    const int q  = lane >> 4;    // quarter 0..3: uint4s q*3..q*3+2 (+tail on q0)
    const int jl = lane & 15;    // pair slot within the 16-chunk
    const int t0 = q * 3;

    const uint4* hwq = ((const uint4*)&s_hwp[wid][0]) + t0;

    float m = -INFINITY, z = 0.f;
    float accx = 0.f, accy = 0.f;

    for (int c = start; c < end; c += CHUNK) {
        const int  cnt = min(CHUNK, end - c);
        const bool pv  = jl < cnt;

        // invalid lanes gather row 0 (finite, in-bounds); e=0 masks it later
        const int nbv = pv ? nbr[c + jl] : 0;
        const uint4* row16 = ((const uint4*)hb) + nbv * (ROWU / 4) + t0;

        // ---- Phase A: f16 quarter-row gather (3x16B + 8B tail), fdot2 ----
        uint4 x0 = row16[0], x1 = row16[1], x2 = row16[2];
        uint4 a0 = hwq[0],   a1 = hwq[1],   a2 = hwq[2];
        uint2 xt, at;
        if (q == 0) {
            xt = *(const uint2*)&hb[nbv * ROWU + 48];   // dims 96..99
            at = *(const uint2*)&s_hwp[wid][48];
        }

        float p0 = 0.f, p1 = 0.f, p2 = 0.f, p3 = 0.f;
        p0 = dot2u(a0.x, x0.x, p0);  p1 = dot2u(a0.y, x0.y, p1);
        p2 = dot2u(a0.z, x0.z, p2);  p3 = dot2u(a0.w, x0.w, p3);
        p0 = dot2u(a1.x, x1.x, p0);  p1 = dot2u(a1.y, x1.y, p1);
        p2 = dot2u(a1.z, x1.z, p2);  p3 = dot2u(a1.w, x1.w, p3);
        p0 = dot2u(a2.x, x2.x, p0);  p1 = dot2u(a2.y, x2.y, p1);
        p2 = dot2u(a2.z, x2.z, p2);  p3 = dot2u(a2.w, x2.w, p3);
        if (q == 0) {
            p0 = dot2u(at.x, xt.x, p0);
            p1 = dot2u(at.y, xt.y, p1);
        }

        // stage raw f16 row to LDS (16B-aligned: ROWU*4 = 208 = 13*16)
        uint4* dst16 = ((uint4*)&s_rows[wid][jl][0]) + t0;
        dst16[0] = x0; dst16[1] = x1; dst16[2] = x2;
        if (q == 0) *(uint2*)&s_rows[wid][jl][48] = xt;

        float part = (p0 + p1) + (p2 + p3);
        part += __shfl_xor(part, 16, 64);    // combine quarters
        part += __shfl_xor(part, 32, 64);
        const float s = pv ? (part >= 0.f ? part : NEG_SLOPE * part)
                           : -INFINITY;

        // ---- online softmax: s duplicated across quarters -> 4-step reductions
        float mx = s;
        #pragma unroll
        for (int off = 8; off >= 1; off >>= 1)
            mx = fmaxf(mx, __shfl_xor(mx, off, 64));
        const float m_new = fmaxf(m, mx);
        const float scale = __expf(m - m_new);         // first chunk: 0
        const float e     = pv ? __expf(s - m_new) : 0.f;
        float es = e;
        #pragma unroll
        for (int off = 8; off >= 1; off >>= 1)
            es += __shfl_xor(es, off, 64);             // sum within 16-group
        z = z * scale + es;
        accx *= scale; accy *= scale;

        if (lane < CHUNK) s_e[wid][lane] = e;          // q0 lanes: jl == lane
        __threadfence_block();                         // LDS stores -> reads

        // ---- Phase B: lane-per-dim accumulate from f16 LDS ----
        const int cnt4 = (cnt + 3) & ~3;               // <= 16
        if (lane < D / 2) {
            for (int j0 = 0; j0 < cnt4; j0 += 4) {
                const float4 ev = *(const float4*)&s_e[wid][j0];  // broadcast
                const unsigned int u0 = s_rows[wid][j0    ][lane];
                const unsigned int u1 = s_rows[wid][j0 + 1][lane];
                const unsigned int u2 = s_rows[wid][j0 + 2][lane];
                const unsigned int u3 = s_rows[wid][j0 + 3][lane];
                accx += ev.x * f16lo(u0);  accy += ev.x * f16hi(u0);
                accx += ev.y * f16lo(u1);  accy += ev.y * f16hi(u1);
                accx += ev.z * f16lo(u2);  accy += ev.z * f16hi(u2);
                accx += ev.w * f16lo(u3);  accy += ev.w * f16hi(u3);
            }
        }
        __threadfence_block();   // phase-B reads done before next chunk's stores
        m = m_new;
    }

    if (lane < D / 2) {
        const float inv = 1.f / z;
        ((float2*)(out + (long)v * D))[lane] = make_float2(accx * inv, accy * inv);
    }
}

extern "C" void kernel_launch(void* const* d_in, const int* in_sizes, int n_in,
                              void* d_out, int out_size, void* d_ws, size_t ws_size,
                              hipStream_t stream) {
    const float* hidden = (const float*)d_in[0];
    const float* W      = (const float*)d_in[1];
    const int*   seg    = (const int*)d_in[2];
    const int*   nbr    = (const int*)d_in[3];
    float*       out    = (float*)d_out;

    const int Ddim = in_sizes[1];           // 100
    const int n    = in_sizes[0] / Ddim;    // 50000
    const int P    = in_sizes[2];           // ~1.3M pairs

    // ws layout: row_ptr (n+1 ints) | hb (n*ROWU uints, 256B-aligned)
    int* row_ptr = (int*)d_ws;
    size_t hb_off = (((size_t)(n + 1) * 4) + 255) & ~(size_t)255;
    unsigned int* hb = (unsigned int*)((char*)d_ws + hb_off);

    hipLaunchKernelGGL(build_row_ptr, dim3((P + 255) / 256), dim3(256), 0, stream,
                       seg, row_ptr, n, P);
    const int total = n * 25;               // float4-groups in hidden
    hipLaunchKernelGGL(cvt_hidden, dim3((total + 255) / 256), dim3(256), 0, stream,
                       hidden, hb, total);
    hipLaunchKernelGGL(gat_agg_kernel, dim3((n + 3) / 4), dim3(256), 0, stream,
                       hidden, W, nbr, row_ptr, hb, out, n);
}